// Round 6
// baseline (380.433 us; speedup 1.0000x reference)
//
#include <hip/hip_runtime.h>

#define TSTEPS 2048
#define BATCH  4096
#define HID    4
#define STRIDE (BATCH*HID)   // 16384 floats per timestep slab
#define PF     8             // x prefetch ring depth (phases)
#define NPHASE 2056          // >= TSTEPS + 2*skew*(L-1) = 2052, padded to 8*257

// Broadcast component k (0..3) to all 4 lanes of each quad via DPP quad_perm.
#define QB(v,k) __int_as_float(__builtin_amdgcn_update_dpp( \
    0, __float_as_int(v), (k)*0x55, 0xF, 0xF, true))

__device__ __forceinline__ float fast_exp2(float x) {
#if __has_builtin(__builtin_amdgcn_exp2f)
  return __builtin_amdgcn_exp2f(x);
#else
  return exp2f(x);
#endif
}
__device__ __forceinline__ float fast_rcp(float x) {
#if __has_builtin(__builtin_amdgcn_rcpf)
  return __builtin_amdgcn_rcpf(x);
#else
  return 1.0f / x;
#endif
}

// Weights pre-scaled by K = 2*log2(e):  tanh(a) = 1 - 2/(1 + exp2(K*a))
__device__ __forceinline__ float actv(float acc) {
  float e = fast_exp2(acc);
  float r = fast_rcp(e + 1.0f);
  return fmaf(-2.0f, r, 1.0f);
}

// One layer step for this lane's component: two parallel 4-FMA chains.
__device__ __forceinline__ float layer_step(const float* __restrict__ wi,
                                            const float* __restrict__ wh,
                                            float b, float vin, float hprev) {
  float ai = b;
  ai = fmaf(QB(vin, 0), wi[0], ai);
  ai = fmaf(QB(vin, 1), wi[1], ai);
  ai = fmaf(QB(vin, 2), wi[2], ai);
  ai = fmaf(QB(vin, 3), wi[3], ai);
  float ah;
  ah =      QB(hprev, 0) * wh[0];
  ah = fmaf(QB(hprev, 1), wh[1], ah);
  ah = fmaf(QB(hprev, 2), wh[2], ah);
  ah = fmaf(QB(hprev, 3), wh[3], ah);
  return actv(ai + ah);
}

// 3-wave layer-systolic pipeline. Wave l (=wid) owns layer l and at phase p
// computes timestep t = p - 2*wid. Handoff h_l -> wave l+1 through a 4-slot
// LDS ring; consumer prefetches one phase early (value written 2 phases ago),
// so LDS latency is fully hidden. One raw s_barrier per phase; explicit
// lgkmcnt(0) drain before it (ds_write visibility). Global x-ring loads stay
// in flight across barriers (no vmcnt drain — this is why __syncthreads() is
// NOT used).
__global__ __launch_bounds__(192) void rnn_pipe(
    const float* __restrict__ X,    // (T, B, H)
    const float* __restrict__ H0,   // (L, B, H)
    const float* __restrict__ Wih,  // (L, H, H)
    const float* __restrict__ Whh,  // (L, H, H)
    const float* __restrict__ bih,  // (L, H)
    const float* __restrict__ bhh,  // (L, H)
    float* __restrict__ Y)          // (T, B, H)
{
  const int lane = threadIdx.x & 63;
  const int wid  = threadIdx.x >> 6;           // 0,1,2 = layer index
  const int g    = blockIdx.x * 64 + lane;     // global (b,j) unit
  const int j    = g & 3;
  const float K  = 2.8853900817779268f;        // 2*log2(e)

  __shared__ float iface[2][4][64];            // [l->l+1 interface][slot][lane]

  // This wave's layer weights (row j), pre-scaled by K.
  float wi[HID], wh[HID], bsum;
#pragma unroll
  for (int k = 0; k < HID; ++k) {
    wi[k] = Wih[(wid*HID + j)*HID + k] * K;
    wh[k] = Whh[(wid*HID + j)*HID + k] * K;
  }
  bsum = (bih[wid*HID + j] + bhh[wid*HID + j]) * K;

  float h_own = H0[wid*STRIDE + g];

  const float* __restrict__ xp = X + g;

  // x prefetch ring (only wave0 consumes/refills; prefill by all waves keeps
  // q defined everywhere — dup reads of 8 slabs are L2-absorbed).
  float q[PF];
#pragma unroll
  for (int u = 0; u < PF; ++u) q[u] = xp[(size_t)u * STRIDE];

  float in_cur = 0.0f;           // this phase's layer input (waves 1,2)
  const int p0 = 2 * wid;        // first valid compute phase for this wave

  for (int po = 0; po < NPHASE / PF; ++po) {
#pragma unroll
    for (int u = 0; u < PF; ++u) {
      const int p = po * PF + u;

      // 1) prefetch next phase's input: value written by producer at p-1
      //    into slot (p-1)&3. Stale reads pre-window are never consumed.
      float in_nxt = 0.0f;
      if (wid != 0) in_nxt = iface[wid - 1][(p + 3) & 3][lane];

      // 2) compute step t = p - 2*wid (garbage outside window, guarded below)
      float vin = (wid == 0) ? q[u] : in_cur;
      float hn  = layer_step(wi, wh, bsum, vin, h_own);
      h_own = (p >= p0) ? hn : h_own;   // don't corrupt state pre-window

      // 3) wave0: refill x ring 8 phases ahead (clamped; tail unused)
      if (wid == 0) {
        int tn = p + PF; if (tn > TSTEPS - 1) tn = TSTEPS - 1;
        q[u] = xp[(size_t)tn * STRIDE];
      }

      // 4) publish: waves 0,1 -> LDS ring; wave 2 -> Y (guarded window)
      if (wid <= 1) {
        iface[wid][p & 3][lane] = h_own;
      } else {
        unsigned t2 = (unsigned)(p - 4);
        if (t2 < (unsigned)TSTEPS) Y[(size_t)t2 * STRIDE + g] = h_own;
      }

      // 5) drain LDS ops (write visibility for the barrier; the prefetch
      //    read was issued a phase-length ago and is already done), rotate,
      //    barrier. sched_barrier(0) fences per rule #18.
      asm volatile("s_waitcnt lgkmcnt(0)" ::: "memory");
      __builtin_amdgcn_sched_barrier(0);
      in_cur = in_nxt;
      __builtin_amdgcn_s_barrier();
      __builtin_amdgcn_sched_barrier(0);
    }
  }
}

extern "C" void kernel_launch(void* const* d_in, const int* in_sizes, int n_in,
                              void* d_out, int out_size, void* d_ws, size_t ws_size,
                              hipStream_t stream) {
  const float* X   = (const float*)d_in[0];
  const float* H0  = (const float*)d_in[1];
  const float* Wih = (const float*)d_in[2];
  const float* Whh = (const float*)d_in[3];
  const float* bih = (const float*)d_in[4];
  const float* bhh = (const float*)d_in[5];
  float* Y = (float*)d_out;

  // 256 blocks x 192 threads: one block per CU, 3 layer-waves on 3 SIMDs.
  rnn_pipe<<<dim3(STRIDE / 64), dim3(192), 0, stream>>>(X, H0, Wih, Whh, bih, bhh, Y);
}

// Round 7
// 281.788 us; speedup vs baseline: 1.3501x; 1.3501x over previous
//
#include <hip/hip_runtime.h>

#define TSTEPS 2048
#define BATCH  4096
#define HID    4
#define STRIDE (BATCH*HID)    // 16384 floats per timestep slab
#define CH     8              // timesteps per chunk (barrier period)
#define NCHUNK (TSTEPS/CH)    // 256 source chunks
#define NPH    (NCHUNK+2)     // 258 phases (pipeline fill/drain), 258 = 3*86

// Broadcast component k (0..3) to all 4 lanes of each quad via DPP quad_perm.
#define QB(v,k) __int_as_float(__builtin_amdgcn_update_dpp( \
    0, __float_as_int(v), (k)*0x55, 0xF, 0xF, true))

__device__ __forceinline__ float fast_exp2(float x) {
#if __has_builtin(__builtin_amdgcn_exp2f)
  return __builtin_amdgcn_exp2f(x);
#else
  return exp2f(x);
#endif
}
__device__ __forceinline__ float fast_rcp(float x) {
#if __has_builtin(__builtin_amdgcn_rcpf)
  return __builtin_amdgcn_rcpf(x);
#else
  return 1.0f / x;
#endif
}

// Weights pre-scaled by K = 2*log2(e):  tanh(a) = 1 - 2/(1 + exp2(K*a))
__device__ __forceinline__ float actv(float acc) {
  float e = fast_exp2(acc);
  float r = fast_rcp(e + 1.0f);
  return fmaf(-2.0f, r, 1.0f);
}

// 3-wave layer-systolic pipeline, chunked: wave l (=wid) owns layer l; at
// phase c it processes source-chunk m = c - l (steps 8m..8m+7). Handoff
// through a double-buffered LDS interface; ONE raw s_barrier per chunk
// (amortized over 8 steps). Explicit lgkmcnt(0) drain before the barrier;
// vmcnt is never drained, so wave0's 3-chunk-deep x prefetch ring stays in
// flight across barriers.
__global__ __launch_bounds__(192) void rnn_pipe(
    const float* __restrict__ X,    // (T, B, H)
    const float* __restrict__ H0,   // (L, B, H)
    const float* __restrict__ Wih,  // (L, H, H)
    const float* __restrict__ Whh,  // (L, H, H)
    const float* __restrict__ bih,  // (L, H)
    const float* __restrict__ bhh,  // (L, H)
    float* __restrict__ Y)          // (T, B, H)
{
  const int lane = threadIdx.x & 63;
  const int wid  = threadIdx.x >> 6;           // 0,1,2 = layer index
  const int g    = blockIdx.x * 64 + lane;     // global (b,j) unit
  const int j    = g & 3;
  const float K  = 2.8853900817779268f;        // 2*log2(e)

  // [interface l->l+1][parity][step-in-chunk][lane] : lane-contiguous b32
  __shared__ float iface[2][2][CH][64];

  // This wave's layer weights (row j), pre-scaled by K.
  float wi[HID], wh[HID], bsum;
#pragma unroll
  for (int k = 0; k < HID; ++k) {
    wi[k] = Wih[(wid*HID + j)*HID + k] * K;
    wh[k] = Whh[(wid*HID + j)*HID + k] * K;
  }
  bsum = (bih[wid*HID + j] + bhh[wid*HID + j]) * K;

  float h = H0[wid*STRIDE + g];

  const float* __restrict__ xp = X + g;
  float* __restrict__ yp = Y + g;

  // x prefetch ring: 3 chunks deep, three statically-named banks (outer loop
  // unrolled by 3 keeps all indices compile-time). Only wave0 consumes and
  // refills; prefill by all waves is harmless (same addresses -> cache hits).
  float q0[CH], q1[CH], q2[CH];
#pragma unroll
  for (int u = 0; u < CH; ++u) q0[u] = xp[(size_t)(0*CH + u) * STRIDE];
#pragma unroll
  for (int u = 0; u < CH; ++u) q1[u] = xp[(size_t)(1*CH + u) * STRIDE];
#pragma unroll
  for (int u = 0; u < CH; ++u) q2[u] = xp[(size_t)(2*CH + u) * STRIDE];

  auto chunk = [&](int c, float (&q)[CH]) {
    // wave-uniform activity window: wave l covers phases l .. NCHUNK-1+l
    if (c >= wid && c <= NCHUNK - 1 + wid) {
      const int m    = c - wid;       // source chunk index
      const int base = m * CH;        // first timestep of this chunk
      const int par  = m & 1;         // double-buffer parity

      // 1) gather this chunk's 8 inputs (recurrence-independent)
      float vin[CH];
      if (wid == 0) {
#pragma unroll
        for (int u = 0; u < CH; ++u) vin[u] = q[u];
        // refill ring 3 chunks ahead (clamped; tail loads unused)
#pragma unroll
        for (int u = 0; u < CH; ++u) {
          int tn = base + 3*CH + u;
          if (tn > TSTEPS - 1) tn = TSTEPS - 1;
          q[u] = xp[(size_t)tn * STRIDE];
        }
      } else {
#pragma unroll
        for (int u = 0; u < CH; ++u) vin[u] = iface[wid-1][par][u][lane];
      }

      // 2) input-side accumulators for all 8 steps: full ILP, off the
      //    recurrence critical path.
      float ai[CH];
#pragma unroll
      for (int u = 0; u < CH; ++u) {
        float a = bsum;
        a = fmaf(QB(vin[u], 0), wi[0], a);
        a = fmaf(QB(vin[u], 1), wi[1], a);
        a = fmaf(QB(vin[u], 2), wi[2], a);
        a = fmaf(QB(vin[u], 3), wi[3], a);
        ai[u] = a;
      }

      // 3) serial recurrence tail: ah = Whh*h, h = tanh-equivalent
#pragma unroll
      for (int u = 0; u < CH; ++u) {
        float ah;
        ah =      QB(h, 0) * wh[0];
        ah = fmaf(QB(h, 1), wh[1], ah);
        ah = fmaf(QB(h, 2), wh[2], ah);
        ah = fmaf(QB(h, 3), wh[3], ah);
        h = actv(ai[u] + ah);
        if (wid <= 1) {
          iface[wid][par][u][lane] = h;
        } else {
          yp[(size_t)(base + u) * STRIDE] = h;
        }
      }
    }

    // phase boundary: drain LDS ops only (NOT vmcnt), then raw barrier.
    __builtin_amdgcn_sched_barrier(0);
    asm volatile("s_waitcnt lgkmcnt(0)" ::: "memory");
    __builtin_amdgcn_sched_barrier(0);
    __builtin_amdgcn_s_barrier();
    __builtin_amdgcn_sched_barrier(0);
  };

  for (int cb = 0; cb < NPH; cb += 3) {   // 258 = 3 * 86
    chunk(cb + 0, q0);
    chunk(cb + 1, q1);
    chunk(cb + 2, q2);
  }
}

extern "C" void kernel_launch(void* const* d_in, const int* in_sizes, int n_in,
                              void* d_out, int out_size, void* d_ws, size_t ws_size,
                              hipStream_t stream) {
  const float* X   = (const float*)d_in[0];
  const float* H0  = (const float*)d_in[1];
  const float* Wih = (const float*)d_in[2];
  const float* Whh = (const float*)d_in[3];
  const float* bih = (const float*)d_in[4];
  const float* bhh = (const float*)d_in[5];
  float* Y = (float*)d_out;

  // 256 blocks x 192 threads: one block per CU, 3 layer-waves on 3 SIMDs.
  rnn_pipe<<<dim3(STRIDE / 64), dim3(192), 0, stream>>>(X, H0, Wih, Whh, bih, bhh, Y);
}

// Round 8
// 220.411 us; speedup vs baseline: 1.7260x; 1.2785x over previous
//
#include <hip/hip_runtime.h>

#define TSTEPS 2048
#define BATCH  4096
#define HID    4
#define STRIDE (BATCH*HID)    // 16384 floats per timestep slab
#define CH     32             // timesteps per chunk (barrier period)
#define NCHUNK (TSTEPS/CH)    // 64 source chunks
#define NPH    (NCHUNK+2)     // 66 phases (fill/drain), even -> unroll by 2

// Broadcast component k (0..3) to all 4 lanes of each quad via DPP quad_perm.
#define QB(v,k) __int_as_float(__builtin_amdgcn_update_dpp( \
    0, __float_as_int(v), (k)*0x55, 0xF, 0xF, true))

__device__ __forceinline__ float fast_exp2(float x) {
#if __has_builtin(__builtin_amdgcn_exp2f)
  return __builtin_amdgcn_exp2f(x);
#else
  return exp2f(x);
#endif
}
__device__ __forceinline__ float fast_rcp(float x) {
#if __has_builtin(__builtin_amdgcn_rcpf)
  return __builtin_amdgcn_rcpf(x);
#else
  return 1.0f / x;
#endif
}

// Weights pre-scaled by K = 2*log2(e):  tanh(a) = 1 - 2/(1 + exp2(K*a))
__device__ __forceinline__ float actv(float acc) {
  float e = fast_exp2(acc);
  float r = fast_rcp(e + 1.0f);
  return fmaf(-2.0f, r, 1.0f);
}

// 3-wave layer-systolic, CH=32 chunks. Wave l (=wid) owns layer l; at phase c
// it processes source chunk m = c - l (steps 32m..32m+31). Handoff through a
// double-buffered LDS interface (slot = m&1); ONE raw s_barrier per phase.
// lgkmcnt(0) drained before the barrier (ds_write visibility); vmcnt is never
// drained, so wave0's two 32-deep x register banks stay in flight across
// phases (coverage = 2 phases >> HBM latency).
__global__ __launch_bounds__(192) void rnn_pipe(
    const float* __restrict__ X,    // (T, B, H)
    const float* __restrict__ H0,   // (L, B, H)
    const float* __restrict__ Wih,  // (L, H, H)
    const float* __restrict__ Whh,  // (L, H, H)
    const float* __restrict__ bih,  // (L, H)
    const float* __restrict__ bhh,  // (L, H)
    float* __restrict__ Y)          // (T, B, H)
{
  const int lane = threadIdx.x & 63;
  const int wid  = threadIdx.x >> 6;           // 0,1,2 = layer index
  const int g    = blockIdx.x * 64 + lane;     // global (b,j) unit
  const int j    = g & 3;
  const float K  = 2.8853900817779268f;        // 2*log2(e)

  // [interface l->l+1][slot = chunk&1][step-in-chunk][lane]
  __shared__ float iface[2][2][CH][64];

  // This wave's layer weights (row j), pre-scaled by K.
  float wi[HID], wh[HID], bsum;
#pragma unroll
  for (int k = 0; k < HID; ++k) {
    wi[k] = Wih[(wid*HID + j)*HID + k] * K;
    wh[k] = Whh[(wid*HID + j)*HID + k] * K;
  }
  bsum = (bih[wid*HID + j] + bhh[wid*HID + j]) * K;

  float h = H0[wid*STRIDE + g];

  const float* __restrict__ xp = X + g;
  float* __restrict__ yp = Y + g;

  // wave0's x double-buffer: bank A = even chunks, bank B = odd chunks.
  float qA[CH], qB[CH];
  if (wid == 0) {
#pragma unroll
    for (int u = 0; u < CH; ++u) qA[u] = xp[(size_t)(0*CH + u) * STRIDE];
#pragma unroll
    for (int u = 0; u < CH; ++u) qB[u] = xp[(size_t)(1*CH + u) * STRIDE];
  }

  // One phase. q = this phase's x bank (wave0 only; consumed then refilled
  // two chunks ahead).
  auto phase = [&](int c, float (&q)[CH]) {
    if (c >= wid && c <= NCHUNK - 1 + wid) {      // wave-uniform window
      const int m    = c - wid;                   // source chunk
      const int base = m * CH;
      const int par  = m & 1;

      // 1) input-side accumulators for all 32 steps (recurrence-independent,
      //    ILP-rich, off the critical path).
      float ai[CH];
      if (wid == 0) {
#pragma unroll
        for (int u = 0; u < CH; ++u) {
          float v = q[u];
          float a = bsum;
          a = fmaf(QB(v, 0), wi[0], a);
          a = fmaf(QB(v, 1), wi[1], a);
          a = fmaf(QB(v, 2), wi[2], a);
          a = fmaf(QB(v, 3), wi[3], a);
          ai[u] = a;
        }
        // refill this bank two chunks ahead (clamped; tail loads unused)
#pragma unroll
        for (int u = 0; u < CH; ++u) {
          int tn = base + 2*CH + u;
          if (tn > TSTEPS - 1) tn = TSTEPS - 1;
          q[u] = xp[(size_t)tn * STRIDE];
        }
      } else {
#pragma unroll
        for (int u = 0; u < CH; ++u) {
          float v = iface[wid-1][par][u][lane];
          float a = bsum;
          a = fmaf(QB(v, 0), wi[0], a);
          a = fmaf(QB(v, 1), wi[1], a);
          a = fmaf(QB(v, 2), wi[2], a);
          a = fmaf(QB(v, 3), wi[3], a);
          ai[u] = a;
        }
      }

      // 2) serial recurrence tail, tree-form dot seeded with ai[u]:
      //    two parallel 2-FMA chains + add -> actv.
#pragma unroll
      for (int u = 0; u < CH; ++u) {
        float t0 = fmaf(QB(h, 0), wh[0], ai[u]);
        float t1 =      QB(h, 1) * wh[1];
        t0 = fmaf(QB(h, 2), wh[2], t0);
        t1 = fmaf(QB(h, 3), wh[3], t1);
        h = actv(t0 + t1);
        if (wid <= 1) {
          iface[wid][par][u][lane] = h;
        } else {
          yp[(size_t)(base + u) * STRIDE] = h;
        }
      }
    }

    // phase boundary: drain LDS writes, then raw barrier (vmcnt untouched).
    __builtin_amdgcn_sched_barrier(0);
    asm volatile("s_waitcnt lgkmcnt(0)" ::: "memory");
    __builtin_amdgcn_s_barrier();
    __builtin_amdgcn_sched_barrier(0);
  };

  for (int cb = 0; cb < NPH; cb += 2) {   // 66 = 2 * 33
    phase(cb + 0, qA);
    phase(cb + 1, qB);
  }
}

extern "C" void kernel_launch(void* const* d_in, const int* in_sizes, int n_in,
                              void* d_out, int out_size, void* d_ws, size_t ws_size,
                              hipStream_t stream) {
  const float* X   = (const float*)d_in[0];
  const float* H0  = (const float*)d_in[1];
  const float* Wih = (const float*)d_in[2];
  const float* Whh = (const float*)d_in[3];
  const float* bih = (const float*)d_in[4];
  const float* bhh = (const float*)d_in[5];
  float* Y = (float*)d_out;

  // 256 blocks x 192 threads: one block per CU, 3 layer-waves on 3 SIMDs.
  rnn_pipe<<<dim3(STRIDE / 64), dim3(192), 0, stream>>>(X, H0, Wih, Whh, bih, bhh, Y);
}

// Round 9
// 202.192 us; speedup vs baseline: 1.8815x; 1.0901x over previous
//
#include <hip/hip_runtime.h>

#define TSTEPS 2048
#define BATCH  4096
#define HID    4
#define STRIDE (BATCH*HID)    // 16384 floats per timestep slab
#define CH     32             // timesteps per chunk (barrier period)
#define NCHUNK (TSTEPS/CH)    // 64 source chunks
#define NPH    (NCHUNK+2)     // 66 phases = 3 * 22 (static xbuf slot rotation)

// Broadcast component k (0..3) to all 4 lanes of each quad via DPP quad_perm.
#define QB(v,k) __int_as_float(__builtin_amdgcn_update_dpp( \
    0, __float_as_int(v), (k)*0x55, 0xF, 0xF, true))

__device__ __forceinline__ float fast_exp2(float x) {
#if __has_builtin(__builtin_amdgcn_exp2f)
  return __builtin_amdgcn_exp2f(x);
#else
  return exp2f(x);
#endif
}
__device__ __forceinline__ float fast_rcp(float x) {
#if __has_builtin(__builtin_amdgcn_rcpf)
  return __builtin_amdgcn_rcpf(x);
#else
  return 1.0f / x;
#endif
}

#if __has_builtin(__builtin_amdgcn_global_load_lds)
#define HAVE_GLL 1
// Direct global->LDS 4B load: LDS dest = base + lane*4 (wave-uniform base),
// global src per-lane. No VGPR liveness -> compiler cannot sink the prefetch.
__device__ __forceinline__ void xload(float* ldst, const float* gsrc) {
  __builtin_amdgcn_global_load_lds(
      (const __attribute__((address_space(1))) void*)gsrc,
      (__attribute__((address_space(3))) void*)ldst, 4, 0, 0);
}
#else
#define HAVE_GLL 0
#endif

// 3-wave layer-systolic, CH=32. Wave l (=wid) owns layer l; phase c processes
// source chunk m = c - wid (steps 32m..32m+31). h handoff through a
// double-buffered LDS interface; ONE raw s_barrier per phase; lgkmcnt(0)
// drained before it, vmcnt NEVER drained in the loop.
//
// Recurrence runs on r = 1/(1+exp2(a)) (h = 1-2r folded into weights):
//   a_t = ai[t] + W'hh . r_{t-1},  W'hh = -2K*Whh,  K = 2*log2(e)
//   ai[t] = K*(Wih.vin_t) + K*(bih+bhh+Whh.1)
// so the serial chain is DPP->fma->fma->add->exp2->add->rcp (no trailing fma).
//
// wave0's x is staged via global_load_lds into a triple-buffered LDS ring,
// issued 2 chunks ahead; consumed after a counted s_waitcnt vmcnt(32).
__global__ __launch_bounds__(192) void rnn_pipe(
    const float* __restrict__ X,    // (T, B, H)
    const float* __restrict__ H0,   // (L, B, H)
    const float* __restrict__ Wih,  // (L, H, H)
    const float* __restrict__ Whh,  // (L, H, H)
    const float* __restrict__ bih,  // (L, H)
    const float* __restrict__ bhh,  // (L, H)
    float* __restrict__ Y)          // (T, B, H)
{
  const int lane = threadIdx.x & 63;
  const int wid  = threadIdx.x >> 6;           // 0,1,2 = layer index
  const int g    = blockIdx.x * 64 + lane;     // global (b,j) unit
  const int j    = g & 3;
  const float K  = 2.8853900817779268f;        // 2*log2(e)

  __shared__ float iface[2][2][CH][64];        // 32 KB: [l->l+1][par][u][lane]
  __shared__ float xbuf[3][CH][64];            // 24 KB: x staging ring (wave0)

  // This wave's layer weights. wi: K*Wih row j. whp: -2K*Whh row j.
  // cb: K*(bih+bhh+Whh.1) (absorbs the h=1-2r substitution).
  float wi[HID], whp[HID], cb;
  {
    float wsum = 0.0f;
#pragma unroll
    for (int k = 0; k < HID; ++k) {
      float whh = Whh[(wid*HID + j)*HID + k];
      whp[k] = -2.0f * K * whh;
      wsum  += whh;
      wi[k]  = Wih[(wid*HID + j)*HID + k] * K;
    }
    cb = (bih[wid*HID + j] + bhh[wid*HID + j] + wsum) * K;
  }

  float r = 0.5f * (1.0f - H0[wid*STRIDE + g]);   // h = 1 - 2r

  const float* __restrict__ xp = X + g;

#if HAVE_GLL
  // Prime the x pipeline: chunks 0,1 -> slots 0,1 (64 outstanding loads).
  if (wid == 0) {
    __builtin_amdgcn_sched_barrier(0);
    asm volatile("s_waitcnt vmcnt(0)" ::: "memory");  // clean vmcnt baseline
#pragma unroll
    for (int u = 0; u < CH; ++u)
      xload(&xbuf[0][u][0], xp + (size_t)(0*CH + u) * STRIDE);
#pragma unroll
    for (int u = 0; u < CH; ++u)
      xload(&xbuf[1][u][0], xp + (size_t)(1*CH + u) * STRIDE);
  }
#endif

  auto phase = [&](int c, int slot) {
    if (c >= wid && c <= NCHUNK - 1 + wid) {      // wave-uniform window
      const int m    = c - wid;                   // source chunk
      const int base = m * CH;
      const int par  = m & 1;

      // 1) input accumulators ai[u] (recurrence-independent, ILP-rich)
      const float* vsrc;
      if (wid == 0) {
#if HAVE_GLL
        // oldest 32 loads (this chunk) have landed in xbuf[slot]
        asm volatile("s_waitcnt vmcnt(32)" ::: "memory");
        __builtin_amdgcn_sched_barrier(0);
        vsrc = &xbuf[slot][0][0];
#else
        vsrc = nullptr;
#endif
      } else {
        vsrc = &iface[wid-1][par][0][0];
      }

      float ai[CH];
#pragma unroll
      for (int u = 0; u < CH; ++u) {
#if HAVE_GLL
        float v = vsrc[u*64 + lane];
#else
        float v = (wid == 0) ? xp[(size_t)(base + u) * STRIDE]
                             : vsrc[u*64 + lane];
#endif
        float a = cb;
        a = fmaf(QB(v, 0), wi[0], a);
        a = fmaf(QB(v, 1), wi[1], a);
        a = fmaf(QB(v, 2), wi[2], a);
        a = fmaf(QB(v, 3), wi[3], a);
        ai[u] = a;
      }

#if HAVE_GLL
      // 2) refill: chunk m+2 -> slot (slot+2)%3 (clamped tail loads unused;
      //    always 32 issues keeps the vmcnt invariant exact)
      if (wid == 0) {
#pragma unroll
        for (int u = 0; u < CH; ++u) {
          int tn = base + 2*CH + u;
          if (tn > TSTEPS - 1) tn = TSTEPS - 1;
          xload(&xbuf[(slot+2)%3][u][0], xp + (size_t)tn * STRIDE);
        }
      }
#endif

      // 3) serial recurrence on r: chain = DPP,fma,fma,add,exp2,add,rcp
#pragma unroll
      for (int u = 0; u < CH; ++u) {
        float t0 = fmaf(QB(r, 0), whp[0], ai[u]);
        float t1 =      QB(r, 1) * whp[1];
        t0 = fmaf(QB(r, 2), whp[2], t0);
        t1 = fmaf(QB(r, 3), whp[3], t1);
        float e = fast_exp2(t0 + t1);
        r = fast_rcp(e + 1.0f);
        float h = fmaf(-2.0f, r, 1.0f);           // off-chain
        if (wid <= 1) {
          iface[wid][par][u][lane] = h;
        } else {
          Y[(size_t)(base + u) * STRIDE + g] = h;
        }
      }
    }

    // phase boundary: drain LDS ops only (NOT vmcnt), then raw barrier.
    __builtin_amdgcn_sched_barrier(0);
    asm volatile("s_waitcnt lgkmcnt(0)" ::: "memory");
    __builtin_amdgcn_s_barrier();
    __builtin_amdgcn_sched_barrier(0);
  };

  for (int cb2 = 0; cb2 < NPH; cb2 += 3) {   // 66 = 3 * 22, static slots
    phase(cb2 + 0, 0);
    phase(cb2 + 1, 1);
    phase(cb2 + 2, 2);
  }
}

extern "C" void kernel_launch(void* const* d_in, const int* in_sizes, int n_in,
                              void* d_out, int out_size, void* d_ws, size_t ws_size,
                              hipStream_t stream) {
  const float* X   = (const float*)d_in[0];
  const float* H0  = (const float*)d_in[1];
  const float* Wih = (const float*)d_in[2];
  const float* Whh = (const float*)d_in[3];
  const float* bih = (const float*)d_in[4];
  const float* bhh = (const float*)d_in[5];
  float* Y = (float*)d_out;

  // 256 blocks x 192 threads: one block per CU, 3 layer-waves on 3 SIMDs.
  rnn_pipe<<<dim3(STRIDE / 64), dim3(192), 0, stream>>>(X, H0, Wih, Whh, bih, bhh, Y);
}